// Round 9
// baseline (359.032 us; speedup 1.0000x reference)
//
#include <hip/hip_runtime.h>
#include <hip/hip_fp16.h>

#define N_NODES 100000
#define N_EDGES 1200000
#define D 64
#define N_CLASSES 16
#define NG8  (N_NODES / 8)         // half-wave groups (final kernel)
#define NG16 (N_NODES / 16)        // quarter-wave groups (gin layers), 6250
#define GRID 2048
#define NXCD 8
#define DRANGE ((N_NODES + NXCD - 1) / NXCD)   // 12500
#define ESRC_CAP 1500032           // >= sum(ceil(deg/4)*4) <= E + 3N
#define SENTINEL N_NODES           // index of the all-zero h row

// ======================= CSR build kernels ================================

// XCD-range-partitioned histogram: block group (blockIdx&7) counts only dst
// in its 12500-node range -> cnt atomics stay in the local XCD's L2.
__global__ __launch_bounds__(256) void hist_kernel(const int* __restrict__ dst,
                                                   int* __restrict__ cnt) {
    int g = blockIdx.x & (NXCD - 1);
    int lo = g * DRANGE, hi = lo + DRANGE;
    int t = (blockIdx.x >> 3) * 256 + threadIdx.x;
    const int NCH = N_EDGES / 4;
    const int STRIDE = (GRID / NXCD) * 256;   // 65536
    for (int c = t; c < NCH; c += STRIDE) {
        int4 d4 = ((const int4*)dst)[c];
        if (d4.x >= lo && d4.x < hi) atomicAdd(&cnt[d4.x], 1);
        if (d4.y >= lo && d4.y < hi) atomicAdd(&cnt[d4.y], 1);
        if (d4.z >= lo && d4.z < hi) atomicAdd(&cnt[d4.z], 1);
        if (d4.w >= lo && d4.w < hi) atomicAdd(&cnt[d4.w], 1);
    }
}

// Exclusive scan over PADDED degrees: pad_deg = ceil(deg/4)*4.
__global__ void scan_block_kernel(const int* __restrict__ cnt,
                                  int* __restrict__ ofs,
                                  int* __restrict__ partial) {
    __shared__ int s[256];
    int tid = threadIdx.x;
    int i = blockIdx.x * 256 + tid;
    int v = (i < N_NODES) ? ((cnt[i] + 3) & ~3) : 0;
    s[tid] = v;
    __syncthreads();
    for (int d = 1; d < 256; d <<= 1) {
        int t = (tid >= d) ? s[tid - d] : 0;
        __syncthreads();
        s[tid] += t;
        __syncthreads();
    }
    if (i < N_NODES) ofs[i] = s[tid] - v;
    if (tid == 255) partial[blockIdx.x] = s[255];
}

__global__ void scan_partials_kernel(int* __restrict__ partial, int nb) {
    __shared__ int s[512];
    int tid = threadIdx.x;
    int v = (tid < nb) ? partial[tid] : 0;
    s[tid] = v;
    __syncthreads();
    for (int d = 1; d < 512; d <<= 1) {
        int t = (tid >= d) ? s[tid - d] : 0;
        __syncthreads();
        s[tid] += t;
        __syncthreads();
    }
    if (tid < nb) partial[tid] = s[tid] - v;
}

// Adds block prefix AND writes the <=3 sentinel pads of each node's segment
// (replaces the full-array fill pass).
__global__ void scan_add_kernel(int* __restrict__ ofs,
                                const int* __restrict__ partial,
                                const int* __restrict__ cnt,
                                int* __restrict__ esrc) {
    int i = blockIdx.x * 256 + threadIdx.x;
    if (i < N_NODES) {
        int o = ofs[i] + partial[blockIdx.x];
        ofs[i] = o;
        int c = cnt[i], p = (c + 3) & ~3;
        for (int j = c; j < p; ++j) esrc[o + j] = SENTINEL;
        if (i == N_NODES - 1) ofs[N_NODES] = o + p;
    }
}

// XCD-range-partitioned scatter: real edges land at the FRONT of each padded
// segment (down-cursor), sentinels already sit in the gap.
__global__ __launch_bounds__(256) void scatter_edges_kernel(
        const int* __restrict__ src,
        const int* __restrict__ dst,
        const int* __restrict__ ofs,
        int* __restrict__ cnt,
        int* __restrict__ esrc) {
    int g = blockIdx.x & (NXCD - 1);
    int lo = g * DRANGE, hi = lo + DRANGE;
    int t = (blockIdx.x >> 3) * 256 + threadIdx.x;
    const int NCH = N_EDGES / 4;
    const int STRIDE = (GRID / NXCD) * 256;
    for (int c = t; c < NCH; c += STRIDE) {
        int4 s4 = ((const int4*)src)[c];
        int4 d4 = ((const int4*)dst)[c];
        if (d4.x >= lo && d4.x < hi) esrc[ofs[d4.x] + atomicSub(&cnt[d4.x], 1) - 1] = s4.x;
        if (d4.y >= lo && d4.y < hi) esrc[ofs[d4.y] + atomicSub(&cnt[d4.y], 1) - 1] = s4.y;
        if (d4.z >= lo && d4.z < hi) esrc[ofs[d4.z] + atomicSub(&cnt[d4.z], 1) - 1] = s4.z;
        if (d4.w >= lo && d4.w < hi) esrc[ofs[d4.w] + atomicSub(&cnt[d4.w], 1) - 1] = s4.w;
    }
}

// ================= f32 -> f16 convert (layer-0 input) =====================
__global__ void cvt_f32_f16_kernel(const float* __restrict__ in, __half* __restrict__ out) {
    const int N4 = N_NODES * D / 4;
    int i = blockIdx.x * 256 + threadIdx.x;
    if (i < N4) {
        float4 v = ((const float4*)in)[i];
        ((__half2*)out)[2 * i + 0] = __floats2half2_rn(v.x, v.y);
        ((__half2*)out)[2 * i + 1] = __floats2half2_rn(v.z, v.w);
    }
}

// Zero row SENTINEL of the three fp16 h buffers.
__global__ void init_zero_rows_kernel(__half* a, __half* b, __half* c) {
    int tid = threadIdx.x;             // 96 threads
    if (tid < 96) {
        __half* p = (tid < 32) ? a : (tid < 64) ? b : c;
        ((unsigned int*)(p + SENTINEL * D))[tid & 31] = 0u;
    }
}

// ============ Fused GIN layer: gather-sum + MLP + relu (fp16 h) ===========
// Quarter-wave layout: 16 lanes per node, lane owns 4 channels (uint2 = 8B).
// Segments padded to multiple of 4 (sentinel -> zero row): no tail, no
// predication. 4-deep body keeps VGPR pressure low; the compiler's natural
// 2x pipelining gives ~8 in flight without the round-8 register blowup.
__global__ __launch_bounds__(256) void gin_layer_kernel(
        const __half* __restrict__ h_in,
        const int* __restrict__ ofs,
        const int* __restrict__ esrc,
        const float* __restrict__ W,
        __half* __restrict__ h_out) {
    __shared__ float Ws[D][D];                       // [in][out], 16KB
    __shared__ __align__(16) float vs[4][4][68];     // +4 pad
    int tid = threadIdx.x;
    for (int k = tid; k < D * D; k += 256)
        Ws[k >> 6][k & 63] = W[k];
    __syncthreads();   // the only barrier
    int w = tid >> 6;
    int lane = tid & 63;
    int q = lane >> 4;         // node within group of 4
    int c4 = lane & 15;        // uint2 slot: channels 4*c4 .. 4*c4+3
    const uint2* hp = (const uint2*)h_in;  // row = 16 uint2

    for (int g = blockIdx.x; g < NG16; g += GRID) {
        int n = g * 16 + w * 4 + q;
        uint2 self = hp[n * 16 + c4];
        float2 sl = __half22float2(*(const __half2*)&self.x);
        float2 sh = __half22float2(*(const __half2*)&self.y);
        float a0 = sl.x, a1 = sl.y, a2 = sh.x, a3 = sh.y;

        int k = ofs[n], end = ofs[n + 1];
        for (; k < end; k += 4) {
            int4 i0 = *(const int4*)(esrc + k);      // 4-aligned
            uint2 r0 = hp[i0.x * 16 + c4];
            uint2 r1 = hp[i0.y * 16 + c4];
            uint2 r2 = hp[i0.z * 16 + c4];
            uint2 r3 = hp[i0.w * 16 + c4];
#define ACC(R) { float2 lo = __half22float2(*(const __half2*)&R.x); \
                 float2 hi = __half22float2(*(const __half2*)&R.y); \
                 a0 += lo.x; a1 += lo.y; a2 += hi.x; a3 += hi.y; }
            ACC(r0) ACC(r1) ACC(r2) ACC(r3)
#undef ACC
        }

        *(float4*)&vs[w][q][4 * c4] = make_float4(a0, a1, a2, a3);
        // wave-local LDS RAW: ordered by lgkmcnt, no barrier
        float o0 = 0.f, o1 = 0.f, o2 = 0.f, o3 = 0.f;
#pragma unroll
        for (int i = 0; i < D; ++i) {
            float vi = vs[w][q][i];                       // broadcast within quarter
            float4 wr = *(const float4*)&Ws[i][4 * c4];   // bcast across quarters
            o0 = fmaf(vi, wr.x, o0); o1 = fmaf(vi, wr.y, o1);
            o2 = fmaf(vi, wr.z, o2); o3 = fmaf(vi, wr.w, o3);
        }
        uint2 ov;
        *(__half2*)&ov.x = __floats2half2_rn(fmaxf(o0, 0.f), fmaxf(o1, 0.f));
        *(__half2*)&ov.y = __floats2half2_rn(fmaxf(o2, 0.f), fmaxf(o3, 0.f));
        ((uint2*)h_out)[n * 16 + c4] = ov;
    }
}

// ============ Final: L2-normalize + 64->16 linear (fp16 in) ===============
__global__ __launch_bounds__(256) void final_kernel(
        const __half* __restrict__ h,
        const float* __restrict__ W_out,
        const float* __restrict__ b_out,
        float* __restrict__ out,    // [N,16]
        float* __restrict__ feat) { // [N,64]
    __shared__ float Wo[D][N_CLASSES];
    __shared__ float fs[4][2][D];
    int tid = threadIdx.x;
    for (int k = tid; k < D * N_CLASSES; k += 256)
        Wo[k >> 4][k & 15] = W_out[k];
    __syncthreads();
    int w = tid >> 6;
    int lane = tid & 63;
    int hh = lane >> 5;
    int c2 = lane & 31;
    const __half2* hp = (const __half2*)h;
    float bias = b_out[lane & 15];

    for (int g = blockIdx.x; g < NG8; g += GRID) {
        int n = g * 8 + w * 2 + hh;
        float2 v = __half22float2(hp[n * 32 + c2]);
        float ss = v.x * v.x + v.y * v.y;
#pragma unroll
        for (int off = 16; off; off >>= 1)   // stays within half-wave
            ss += __shfl_xor(ss, off);
        float rinv = 1.f / fmaxf(sqrtf(ss), 1e-12f);
        float f0 = v.x * rinv, f1 = v.y * rinv;
        ((float2*)feat)[n * 32 + c2] = make_float2(f0, f1);
        fs[w][hh][2 * c2 + 0] = f0;
        fs[w][hh][2 * c2 + 1] = f1;
        // wave-local LDS RAW: no barrier
        if (c2 < N_CLASSES) {
            float acc = bias;
#pragma unroll
            for (int i = 0; i < D; ++i)
                acc = fmaf(fs[w][hh][i], Wo[i][c2], acc);
            out[n * N_CLASSES + c2] = acc;
        }
    }
}

// ==========================================================================
extern "C" void kernel_launch(void* const* d_in, const int* in_sizes, int n_in,
                              void* d_out, int out_size, void* d_ws, size_t ws_size,
                              hipStream_t stream) {
    const float* x     = (const float*)d_in[0];
    const int*   src   = (const int*)d_in[1];
    const int*   dst   = (const int*)d_in[2];
    const float* W0    = (const float*)d_in[3];
    const float* W1    = (const float*)d_in[4];
    const float* W2    = (const float*)d_in[5];
    const float* W_out = (const float*)d_in[6];
    const float* b_out = (const float*)d_in[7];

    float* out  = (float*)d_out;                                  // [N,16]
    float* feat = (float*)d_out + (size_t)N_NODES * N_CLASSES;    // [N,64]

    const int NB_NODE = (N_NODES + 255) / 256;       // 391
    const int NB_CVT  = (N_NODES * D / 4 + 255) / 256;

    // ws layout (256B-aligned slabs); h buffers have N_NODES+1 rows (zero row)
    size_t off = 0;
    auto alloc = [&](size_t bytes) { size_t o = off; off = (off + bytes + 255) & ~(size_t)255; return o; };
    size_t o_cnt     = alloc((size_t)N_NODES * 4);
    size_t o_partial = alloc(512 * 4);
    size_t o_ofs     = alloc(((size_t)N_NODES + 1) * 4);
    size_t o_esrc    = alloc((size_t)ESRC_CAP * 4);
    size_t o_x16     = alloc((size_t)(N_NODES + 1) * D * 2);
    size_t o_bufA    = alloc((size_t)(N_NODES + 1) * D * 2);
    size_t o_bufB    = alloc((size_t)(N_NODES + 1) * D * 2);

    char* w8 = (char*)d_ws;
    int*    cnt     = (int*)(w8 + o_cnt);
    int*    partial = (int*)(w8 + o_partial);
    int*    ofs     = (int*)(w8 + o_ofs);
    int*    esrc    = (int*)(w8 + o_esrc);
    __half* x16     = (__half*)(w8 + o_x16);
    __half* bufA    = (__half*)(w8 + o_bufA);
    __half* bufB    = (__half*)(w8 + o_bufB);

    // --- padded CSR build (once, reused by 3 layers) ---
    hipMemsetAsync(cnt, 0, (size_t)N_NODES * 4, stream);
    hist_kernel<<<GRID, 256, 0, stream>>>(dst, cnt);
    scan_block_kernel<<<NB_NODE, 256, 0, stream>>>(cnt, ofs, partial);
    scan_partials_kernel<<<1, 512, 0, stream>>>(partial, NB_NODE);
    scan_add_kernel<<<NB_NODE, 256, 0, stream>>>(ofs, partial, cnt, esrc);
    scatter_edges_kernel<<<GRID, 256, 0, stream>>>(src, dst, ofs, cnt, esrc);

    // --- x -> fp16; zero rows for sentinel ---
    cvt_f32_f16_kernel<<<NB_CVT, 256, 0, stream>>>(x, x16);
    init_zero_rows_kernel<<<1, 96, 0, stream>>>(x16, bufA, bufB);

    // --- 3 fused GIN layers, then final ---
    gin_layer_kernel<<<GRID, 256, 0, stream>>>(x16,  ofs, esrc, W0, bufA);
    gin_layer_kernel<<<GRID, 256, 0, stream>>>(bufA, ofs, esrc, W1, bufB);
    gin_layer_kernel<<<GRID, 256, 0, stream>>>(bufB, ofs, esrc, W2, bufA);
    final_kernel<<<GRID, 256, 0, stream>>>(bufA, W_out, b_out, out, feat);
}

// Round 10
// 260.749 us; speedup vs baseline: 1.3769x; 1.3769x over previous
//
#include <hip/hip_runtime.h>
#include <hip/hip_fp16.h>

#define N_NODES 100000
#define N_EDGES 1200000
#define D 64
#define N_CLASSES 16
#define NG8  (N_NODES / 8)
#define GRID 2048
#define NXCD 8
#define DRANGE ((N_NODES + NXCD - 1) / NXCD)   // 12500
#define ESRC_CAP 1900032           // >= E + 7N (pad-8)
#define SENTINEL N_NODES           // index of the all-zero h row
#define NB_CVT 6250                // 100000*64/4 float4 elems / 256

typedef _Float16 f16x8 __attribute__((ext_vector_type(8)));
typedef float f32x4 __attribute__((ext_vector_type(4)));

// ======================= CSR build kernels ================================

// XCD-range-partitioned histogram: cnt atomics stay in the local XCD's L2.
__global__ __launch_bounds__(256) void hist_kernel(const int* __restrict__ dst,
                                                   int* __restrict__ cnt) {
    int g = blockIdx.x & (NXCD - 1);
    int lo = g * DRANGE, hi = lo + DRANGE;
    int t = (blockIdx.x >> 3) * 256 + threadIdx.x;
    const int NCH = N_EDGES / 4;
    const int STRIDE = (GRID / NXCD) * 256;
    for (int c = t; c < NCH; c += STRIDE) {
        int4 d4 = ((const int4*)dst)[c];
        if (d4.x >= lo && d4.x < hi) atomicAdd(&cnt[d4.x], 1);
        if (d4.y >= lo && d4.y < hi) atomicAdd(&cnt[d4.y], 1);
        if (d4.z >= lo && d4.z < hi) atomicAdd(&cnt[d4.z], 1);
        if (d4.w >= lo && d4.w < hi) atomicAdd(&cnt[d4.w], 1);
    }
}

// Exclusive scan over PADDED degrees: pad_deg = ceil(deg/8)*8.
__global__ void scan_block_kernel(const int* __restrict__ cnt,
                                  int* __restrict__ ofs,
                                  int* __restrict__ partial) {
    __shared__ int s[256];
    int tid = threadIdx.x;
    int i = blockIdx.x * 256 + tid;
    int v = (i < N_NODES) ? ((cnt[i] + 7) & ~7) : 0;
    s[tid] = v;
    __syncthreads();
    for (int d = 1; d < 256; d <<= 1) {
        int t = (tid >= d) ? s[tid - d] : 0;
        __syncthreads();
        s[tid] += t;
        __syncthreads();
    }
    if (i < N_NODES) ofs[i] = s[tid] - v;
    if (tid == 255) partial[blockIdx.x] = s[255];
}

__global__ void scan_partials_kernel(int* __restrict__ partial, int nb) {
    __shared__ int s[512];
    int tid = threadIdx.x;
    int v = (tid < nb) ? partial[tid] : 0;
    s[tid] = v;
    __syncthreads();
    for (int d = 1; d < 512; d <<= 1) {
        int t = (tid >= d) ? s[tid - d] : 0;
        __syncthreads();
        s[tid] += t;
        __syncthreads();
    }
    if (tid < nb) partial[tid] = s[tid] - v;
}

// Adds block prefix AND writes the <=7 sentinel pads of each node's segment.
__global__ void scan_add_kernel(int* __restrict__ ofs,
                                const int* __restrict__ partial,
                                const int* __restrict__ cnt,
                                int* __restrict__ esrc) {
    int i = blockIdx.x * 256 + threadIdx.x;
    if (i < N_NODES) {
        int o = ofs[i] + partial[blockIdx.x];
        ofs[i] = o;
        int c = cnt[i], p = (c + 7) & ~7;
        for (int j = c; j < p; ++j) esrc[o + j] = SENTINEL;
        if (i == N_NODES - 1) ofs[N_NODES] = o + p;
    }
}

// XCD-range-partitioned scatter (down-cursor on cnt).
__global__ __launch_bounds__(256) void scatter_edges_kernel(
        const int* __restrict__ src,
        const int* __restrict__ dst,
        const int* __restrict__ ofs,
        int* __restrict__ cnt,
        int* __restrict__ esrc) {
    int g = blockIdx.x & (NXCD - 1);
    int lo = g * DRANGE, hi = lo + DRANGE;
    int t = (blockIdx.x >> 3) * 256 + threadIdx.x;
    const int NCH = N_EDGES / 4;
    const int STRIDE = (GRID / NXCD) * 256;
    for (int c = t; c < NCH; c += STRIDE) {
        int4 s4 = ((const int4*)src)[c];
        int4 d4 = ((const int4*)dst)[c];
        if (d4.x >= lo && d4.x < hi) esrc[ofs[d4.x] + atomicSub(&cnt[d4.x], 1) - 1] = s4.x;
        if (d4.y >= lo && d4.y < hi) esrc[ofs[d4.y] + atomicSub(&cnt[d4.y], 1) - 1] = s4.y;
        if (d4.z >= lo && d4.z < hi) esrc[ofs[d4.z] + atomicSub(&cnt[d4.z], 1) - 1] = s4.z;
        if (d4.w >= lo && d4.w < hi) esrc[ofs[d4.w] + atomicSub(&cnt[d4.w], 1) - 1] = s4.w;
    }
}

// ====== Prep: x->fp16, W0..W2->fp16, zero sentinel rows (one kernel) ======
__global__ void prep_kernel(const float* __restrict__ x,
                            const float* __restrict__ W0,
                            const float* __restrict__ W1,
                            const float* __restrict__ W2,
                            __half* __restrict__ x16,
                            __half* __restrict__ w16,   // [3][4096]
                            __half* __restrict__ bufA,
                            __half* __restrict__ bufB) {
    int b = blockIdx.x;
    if (b < NB_CVT) {
        int i = b * 256 + threadIdx.x;
        float4 v = ((const float4*)x)[i];
        ((__half2*)x16)[2 * i + 0] = __floats2half2_rn(v.x, v.y);
        ((__half2*)x16)[2 * i + 1] = __floats2half2_rn(v.z, v.w);
    } else if (b < NB_CVT + 3) {
        int l = b - NB_CVT;
        const float* W = (l == 0) ? W0 : (l == 1) ? W1 : W2;
        for (int j = threadIdx.x; j < D * D; j += 256)
            w16[l * D * D + j] = __float2half(W[j]);
    } else {
        int tid = threadIdx.x;
        if (tid < 96) {
            __half* p = (tid < 32) ? x16 : (tid < 64) ? bufA : bufB;
            ((unsigned int*)(p + SENTINEL * D))[tid & 31] = 0u;
        }
    }
}

// ================= Gather: S[n] = h[n] + sum_neighbors h ==================
// Pure gather, no LDS, no barrier. Quarter-wave: 16 lanes/node, lane owns 4
// channels (uint2). Segments padded to 8 with sentinel (zero row).
__global__ __launch_bounds__(256) void gather_kernel(
        const __half* __restrict__ h_in,
        const int* __restrict__ ofs,
        const int* __restrict__ esrc,
        __half* __restrict__ s_out) {
    int w = threadIdx.x >> 6, lane = threadIdx.x & 63;
    int q = lane >> 4;
    int c4 = lane & 15;
    int n = blockIdx.x * 16 + w * 4 + q;   // grid 6250 -> n < 100000 exact
    const uint2* hp = (const uint2*)h_in;

    uint2 self = hp[n * 16 + c4];
    float2 sl = __half22float2(*(const __half2*)&self.x);
    float2 sh = __half22float2(*(const __half2*)&self.y);
    float a0 = sl.x, a1 = sl.y, a2 = sh.x, a3 = sh.y;

    int k = ofs[n], end = ofs[n + 1];
    for (; k < end; k += 8) {
        int4 i0 = *(const int4*)(esrc + k);
        int4 i1 = *(const int4*)(esrc + k + 4);
        uint2 r0 = hp[i0.x * 16 + c4];
        uint2 r1 = hp[i0.y * 16 + c4];
        uint2 r2 = hp[i0.z * 16 + c4];
        uint2 r3 = hp[i0.w * 16 + c4];
        uint2 r4 = hp[i1.x * 16 + c4];
        uint2 r5 = hp[i1.y * 16 + c4];
        uint2 r6 = hp[i1.z * 16 + c4];
        uint2 r7 = hp[i1.w * 16 + c4];
#define ACC(R) { float2 lo = __half22float2(*(const __half2*)&R.x); \
                 float2 hi = __half22float2(*(const __half2*)&R.y); \
                 a0 += lo.x; a1 += lo.y; a2 += hi.x; a3 += hi.y; }
        ACC(r0) ACC(r1) ACC(r2) ACC(r3) ACC(r4) ACC(r5) ACC(r6) ACC(r7)
#undef ACC
    }
    uint2 ov;
    *(__half2*)&ov.x = __floats2half2_rn(a0, a1);
    *(__half2*)&ov.y = __floats2half2_rn(a2, a3);
    ((uint2*)s_out)[n * 16 + c4] = ov;
}

// ================= MLP: h' = relu(S @ W) via MFMA =========================
// Wave = 16-node tile. W lives in 8 B-fragments (32 VGPR), loaded once.
// A: lane holds S[t*16 + (lane&15)][kt*32 + (lane>>4)*8 + j]
// B: lane holds W[kt*32 + (lane>>4)*8 + j][ct*16 + (lane&15)]
// D: row=(lane>>4)*4+r, col=ct*16+(lane&15)   [m89-verified layout]
__global__ __launch_bounds__(256) void mlp_kernel(
        const __half* __restrict__ S,
        const __half* __restrict__ W16,   // [64][64] fp16 [in][out]
        __half* __restrict__ h_out) {
    int w = threadIdx.x >> 6, lane = threadIdx.x & 63;
    int m = lane & 15;
    int kg = lane >> 4;
    const _Float16* Wp = (const _Float16*)W16;
    f16x8 bf[4][2];
#pragma unroll
    for (int ct = 0; ct < 4; ++ct)
#pragma unroll
        for (int kt = 0; kt < 2; ++kt)
#pragma unroll
            for (int j = 0; j < 8; ++j)
                bf[ct][kt][j] = Wp[(kt * 32 + kg * 8 + j) * D + ct * 16 + m];

    int t = blockIdx.x * 4 + w;
    if (t >= N_NODES / 16) return;
    const _Float16* Sp = (const _Float16*)S;
    int row = t * 16 + m;
    f16x8 a0 = *(const f16x8*)(Sp + row * D + kg * 8);
    f16x8 a1 = *(const f16x8*)(Sp + row * D + 32 + kg * 8);
    f32x4 c[4];
#pragma unroll
    for (int ct = 0; ct < 4; ++ct) {
        f32x4 z = {0.f, 0.f, 0.f, 0.f};
        z = __builtin_amdgcn_mfma_f32_16x16x32_f16(a0, bf[ct][0], z, 0, 0, 0);
        z = __builtin_amdgcn_mfma_f32_16x16x32_f16(a1, bf[ct][1], z, 0, 0, 0);
        c[ct] = z;
    }
#pragma unroll
    for (int ct = 0; ct < 4; ++ct)
#pragma unroll
        for (int r = 0; r < 4; ++r)
            h_out[(t * 16 + kg * 4 + r) * D + ct * 16 + m] =
                __float2half(fmaxf(c[ct][r], 0.f));
}

// ============ Final: L2-normalize + 64->16 linear (fp16 in) ===============
__global__ __launch_bounds__(256) void final_kernel(
        const __half* __restrict__ h,
        const float* __restrict__ W_out,
        const float* __restrict__ b_out,
        float* __restrict__ out,    // [N,16]
        float* __restrict__ feat) { // [N,64]
    __shared__ float Wo[D][N_CLASSES];
    __shared__ float fs[4][2][D];
    int tid = threadIdx.x;
    for (int k = tid; k < D * N_CLASSES; k += 256)
        Wo[k >> 4][k & 15] = W_out[k];
    __syncthreads();
    int w = tid >> 6;
    int lane = tid & 63;
    int hh = lane >> 5;
    int c2 = lane & 31;
    const __half2* hp = (const __half2*)h;
    float bias = b_out[lane & 15];

    for (int g = blockIdx.x; g < NG8; g += GRID) {
        int n = g * 8 + w * 2 + hh;
        float2 v = __half22float2(hp[n * 32 + c2]);
        float ss = v.x * v.x + v.y * v.y;
#pragma unroll
        for (int off = 16; off; off >>= 1)
            ss += __shfl_xor(ss, off);
        float rinv = 1.f / fmaxf(sqrtf(ss), 1e-12f);
        float f0 = v.x * rinv, f1 = v.y * rinv;
        ((float2*)feat)[n * 32 + c2] = make_float2(f0, f1);
        fs[w][hh][2 * c2 + 0] = f0;
        fs[w][hh][2 * c2 + 1] = f1;
        if (c2 < N_CLASSES) {
            float acc = bias;
#pragma unroll
            for (int i = 0; i < D; ++i)
                acc = fmaf(fs[w][hh][i], Wo[i][c2], acc);
            out[n * N_CLASSES + c2] = acc;
        }
    }
}

// ==========================================================================
extern "C" void kernel_launch(void* const* d_in, const int* in_sizes, int n_in,
                              void* d_out, int out_size, void* d_ws, size_t ws_size,
                              hipStream_t stream) {
    const float* x     = (const float*)d_in[0];
    const int*   src   = (const int*)d_in[1];
    const int*   dst   = (const int*)d_in[2];
    const float* W0    = (const float*)d_in[3];
    const float* W1    = (const float*)d_in[4];
    const float* W2    = (const float*)d_in[5];
    const float* W_out = (const float*)d_in[6];
    const float* b_out = (const float*)d_in[7];

    float* out  = (float*)d_out;
    float* feat = (float*)d_out + (size_t)N_NODES * N_CLASSES;

    const int NB_NODE = (N_NODES + 255) / 256;       // 391
    const int NB_MLP  = (N_NODES / 16 + 3) / 4;      // 1563

    // ws layout; h buffers have N_NODES+1 rows (sentinel zero row)
    size_t off = 0;
    auto alloc = [&](size_t bytes) { size_t o = off; off = (off + bytes + 255) & ~(size_t)255; return o; };
    size_t o_cnt     = alloc((size_t)N_NODES * 4);
    size_t o_partial = alloc(512 * 4);
    size_t o_ofs     = alloc(((size_t)N_NODES + 1) * 4);
    size_t o_esrc    = alloc((size_t)ESRC_CAP * 4);
    size_t o_w16     = alloc((size_t)3 * D * D * 2);
    size_t o_X       = alloc((size_t)(N_NODES + 1) * D * 2);
    size_t o_A       = alloc((size_t)(N_NODES + 1) * D * 2);
    size_t o_B       = alloc((size_t)(N_NODES + 1) * D * 2);

    char* w8 = (char*)d_ws;
    int*    cnt     = (int*)(w8 + o_cnt);
    int*    partial = (int*)(w8 + o_partial);
    int*    ofs     = (int*)(w8 + o_ofs);
    int*    esrc    = (int*)(w8 + o_esrc);
    __half* w16     = (__half*)(w8 + o_w16);
    __half* X       = (__half*)(w8 + o_X);
    __half* A       = (__half*)(w8 + o_A);
    __half* B       = (__half*)(w8 + o_B);

    // --- padded CSR build ---
    hipMemsetAsync(cnt, 0, (size_t)N_NODES * 4, stream);
    hist_kernel<<<GRID, 256, 0, stream>>>(dst, cnt);
    scan_block_kernel<<<NB_NODE, 256, 0, stream>>>(cnt, ofs, partial);
    scan_partials_kernel<<<1, 512, 0, stream>>>(partial, NB_NODE);
    scan_add_kernel<<<NB_NODE, 256, 0, stream>>>(ofs, partial, cnt, esrc);
    scatter_edges_kernel<<<GRID, 256, 0, stream>>>(src, dst, ofs, cnt, esrc);

    // --- prep: x->fp16, W->fp16, zero sentinel rows ---
    prep_kernel<<<NB_CVT + 4, 256, 0, stream>>>(x, W0, W1, W2, X, w16, A, B);

    // --- 3 layers: gather then MFMA MLP; buffers rotate X->A->B ---
    gather_kernel<<<N_NODES / 16, 256, 0, stream>>>(X, ofs, esrc, A);       // S1=A
    mlp_kernel<<<NB_MLP, 256, 0, stream>>>(A, w16 + 0 * D * D, B);          // h1=B
    gather_kernel<<<N_NODES / 16, 256, 0, stream>>>(B, ofs, esrc, X);       // S2=X
    mlp_kernel<<<NB_MLP, 256, 0, stream>>>(X, w16 + 1 * D * D, A);          // h2=A
    gather_kernel<<<N_NODES / 16, 256, 0, stream>>>(A, ofs, esrc, B);       // S3=B
    mlp_kernel<<<NB_MLP, 256, 0, stream>>>(B, w16 + 2 * D * D, X);          // h3=X

    final_kernel<<<GRID, 256, 0, stream>>>(X, W_out, b_out, out, feat);
}